// Round 1
// baseline (1761.241 us; speedup 1.0000x reference)
//
#include <hip/hip_runtime.h>

static constexpr int BLK = 256;
#define PI_F 3.14159265358979323846f

__global__ __launch_bounds__(BLK) void compact_k(const float* __restrict__ r, int E,
                                                 int* __restrict__ cnt, int* __restrict__ list) {
  int e = blockIdx.x * BLK + threadIdx.x;
  if (e >= E) return;
  float rx = r[3*e], ry = r[3*e+1], rz = r[3*e+2];
  float xsq = (rx*rx + ry*ry + rz*rz) * (1.0f/2.5f);
  if (xsq < 1.0f) {
    int p = atomicAdd(cnt, 1);
    list[p] = e;
  }
}

__global__ __launch_bounds__(BLK) void msg_k(
    const float* __restrict__ r_ij,
    const float* __restrict__ x_a,
    const float* __restrict__ x_v,
    const float* __restrict__ x_d,
    const float* __restrict__ P000, const float* __restrict__ P110, const float* __restrict__ P220,
    const float* __restrict__ P011, const float* __restrict__ P101, const float* __restrict__ P121,
    const float* __restrict__ P211, const float* __restrict__ P111,
    const float* __restrict__ P022, const float* __restrict__ P202, const float* __restrict__ P112,
    const float* __restrict__ P222, const float* __restrict__ P212,
    const int* __restrict__ src, const int* __restrict__ dst,
    const int* __restrict__ cnt, const int* __restrict__ list,
    int E, int N,
    float* __restrict__ out)
{
  const int t = blockIdx.x * BLK + threadIdx.x;
  int e;
  if (list != nullptr) {
    if (t >= *cnt) return;
    e = list[t];
  } else {
    if (t >= E) return;
    e = t;
  }

  const float rx = r_ij[3*e], ry = r_ij[3*e+1], rz = r_ij[3*e+2];
  const float xsq = (rx*rx + ry*ry + rz*rz) * (1.0f/2.5f);
  const float cut = 1.0f - xsq;
  if (cut <= 0.0f) return;   // relu(1-xsq)=0 -> all phi=0 -> psi=0

  // enc[l] = cos(l*pi*sqrt(xsq)) * cut  (Chebyshev recurrence, one cosf)
  float enc[8];
  {
    const float th = PI_F * sqrtf(xsq);
    const float c1 = cosf(th);
    enc[0] = cut;
    enc[1] = c1 * cut;
    float cp = 1.0f, cc = c1;
    #pragma unroll
    for (int n = 2; n < 8; n++) { float cn = 2.0f*c1*cc - cp; cp = cc; cc = cn; enc[n] = cn*cut; }
  }
  // rhat = y/sqrt(1+|y|^2), y = r*(7/R0)
  float h0, h1, h2;
  {
    const float s = 7.0f/2.5f;
    const float yx = rx*s, yy = ry*s, yz = rz*s;
    const float inv = rsqrtf(1.0f + yx*yx + yy*yy + yz*yz);
    h0 = yx*inv; h1 = yy*inv; h2 = yz*inv;
  }

  const int nj = dst[e];
  const int ni = src[e];
  const float* __restrict__ xaj = x_a + (size_t)nj*32;
  const float* __restrict__ xvj = x_v + (size_t)nj*48;
  const float* __restrict__ xdj = x_d + (size_t)nj*72;

  float* outA = out + (size_t)ni*32;
  float* outV = out + (size_t)N*32 + (size_t)ni*48;
  float* outD = out + (size_t)N*80 + (size_t)ni*72;

  // ---- scalar channel vector c[56] = [xa_j (32) | s1=h.xv (16) | s2=h^T xd h (8)]
  float c[56];
  #pragma unroll
  for (int b = 0; b < 32; b++) c[b] = xaj[b];
  #pragma unroll
  for (int b = 0; b < 16; b++)
    c[32+b] = h0*xvj[3*b] + h1*xvj[3*b+1] + h2*xvj[3*b+2];
  #pragma unroll
  for (int b = 0; b < 8; b++) {
    const float* m = xdj + 9*b;
    float t0 = h0*m[0] + h1*m[3] + h2*m[6];
    float t1 = h0*m[1] + h1*m[4] + h2*m[7];
    float t2 = h0*m[2] + h1*m[5] + h2*m[8];
    c[48+b] = h0*t0 + h1*t1 + h2*t2;
  }

  // ---- psi_a : P_000 (b=32 on xa) + P_110 (b=16 on s1) + P_220 (b=8 on s2)
  #pragma unroll 2
  for (int a = 0; a < 32; a++) {
    float acc = 0.0f;
    #pragma unroll
    for (int l = 0; l < 8; l++) {
      const float* p0 = P000 + (a*8 + l)*32;
      const float* p1 = P110 + (a*8 + l)*16;
      const float* p2 = P220 + (a*8 + l)*8;
      float s = 0.0f;
      #pragma unroll
      for (int b = 0; b < 32; b++) s += p0[b]*c[b];
      #pragma unroll
      for (int b = 0; b < 16; b++) s += p1[b]*c[32+b];
      #pragma unroll
      for (int b = 0; b < 8; b++)  s += p2[b]*c[48+b];
      acc += enc[l]*s;
    }
    atomicAdd(outA + a, 0.1f*acc);
  }

  // ---- scalar parts while c is alive: scv (P_101 xa + P_211 s1), scd (P_202 xa)
  float scv[16];
  #pragma unroll 2
  for (int v = 0; v < 16; v++) {
    float acc = 0.0f;
    #pragma unroll
    for (int l = 0; l < 8; l++) {
      const float* pa = P101 + (v*8 + l)*32;
      const float* pb = P211 + (v*8 + l)*16;
      float s = 0.0f;
      #pragma unroll
      for (int b = 0; b < 32; b++) s += pa[b]*c[b];
      #pragma unroll
      for (int b = 0; b < 16; b++) s += pb[b]*c[32+b];
      acc += enc[l]*s;
    }
    scv[v] = acc;
  }
  float scd[8];
  #pragma unroll 2
  for (int d = 0; d < 8; d++) {
    float acc = 0.0f;
    #pragma unroll
    for (int l = 0; l < 8; l++) {
      const float* p = P202 + (d*8 + l)*32;
      float s = 0.0f;
      #pragma unroll
      for (int b = 0; b < 32; b++) s += p[b]*c[b];
      acc += enc[l]*s;
    }
    scd[d] = acc;
  }

  // ---- vector channels: V = xv_j, CR = h x xv_j, T = h^T xd_j (contract first index)
  float V0[16], V1[16], V2[16], C0[16], C1[16], C2[16];
  #pragma unroll
  for (int b = 0; b < 16; b++) {
    float v0 = xvj[3*b], v1 = xvj[3*b+1], v2 = xvj[3*b+2];
    V0[b] = v0; V1[b] = v1; V2[b] = v2;
    C0[b] = h1*v2 - h2*v1;
    C1[b] = h2*v0 - h0*v2;
    C2[b] = h0*v1 - h1*v0;
  }
  float T0[8], T1[8], T2v[8];
  #pragma unroll
  for (int b = 0; b < 8; b++) {
    const float* m = xdj + 9*b;
    T0[b]  = h0*m[0] + h1*m[3] + h2*m[6];
    T1[b]  = h0*m[1] + h1*m[4] + h2*m[7];
    T2v[b] = h0*m[2] + h1*m[5] + h2*m[8];
  }

  // ---- psi_v : P_011 (xv) + P_121 (T) + P_111 (CR), plus rhat * scv
  #pragma unroll 2
  for (int v = 0; v < 16; v++) {
    float a0 = 0, a1 = 0, a2 = 0;
    #pragma unroll
    for (int l = 0; l < 8; l++) {
      const float el = enc[l];
      const float* p011 = P011 + (v*8 + l)*16;
      const float* p121 = P121 + (v*8 + l)*8;
      const float* p111 = P111 + (v*8 + l)*16;
      float s0 = 0, s1 = 0, s2 = 0;
      #pragma unroll
      for (int b = 0; b < 16; b++) { float p = p011[b]; s0 += p*V0[b]; s1 += p*V1[b]; s2 += p*V2[b]; }
      #pragma unroll
      for (int b = 0; b < 8;  b++) { float p = p121[b]; s0 += p*T0[b]; s1 += p*T1[b]; s2 += p*T2v[b]; }
      #pragma unroll
      for (int b = 0; b < 16; b++) { float p = p111[b]; s0 += p*C0[b]; s1 += p*C1[b]; s2 += p*C2[b]; }
      a0 += el*s0; a1 += el*s1; a2 += el*s2;
    }
    const float sv = scv[v];
    atomicAdd(outV + v*3 + 0, 0.1f*(a0 + h0*sv));
    atomicAdd(outV + v*3 + 1, 0.1f*(a1 + h1*sv));
    atomicAdd(outV + v*3 + 2, 0.1f*(a2 + h2*sv));
  }

  // ---- Q[d][j] = sum_l enc_l * ( P_112·xv[:,j] + P_222·T[:,j] + P_212·CR[:,j] )
  float Q0[8], Q1[8], Q2[8];
  #pragma unroll 2
  for (int d = 0; d < 8; d++) {
    float a0 = 0, a1 = 0, a2 = 0;
    #pragma unroll
    for (int l = 0; l < 8; l++) {
      const float el = enc[l];
      const float* p112 = P112 + (d*8 + l)*16;
      const float* p222 = P222 + (d*8 + l)*8;
      const float* p212 = P212 + (d*8 + l)*16;
      float s0 = 0, s1 = 0, s2 = 0;
      #pragma unroll
      for (int b = 0; b < 16; b++) { float p = p112[b]; s0 += p*V0[b]; s1 += p*V1[b]; s2 += p*V2[b]; }
      #pragma unroll
      for (int b = 0; b < 8;  b++) { float p = p222[b]; s0 += p*T0[b]; s1 += p*T1[b]; s2 += p*T2v[b]; }
      #pragma unroll
      for (int b = 0; b < 16; b++) { float p = p212[b]; s0 += p*C0[b]; s1 += p*C1[b]; s2 += p*C2[b]; }
      a0 += el*s0; a1 += el*s1; a2 += el*s2;
    }
    Q0[d] = a0; Q1[d] = a1; Q2[d] = a2;
  }

  // ---- psi_d : P_022 full tensor + rhat_i*Q[d][j] + rhat_i*rhat_j*scd[d]
  float X[8][9];
  #pragma unroll
  for (int b = 0; b < 8; b++) {
    #pragma unroll
    for (int k = 0; k < 9; k++) X[b][k] = xdj[9*b + k];
  }
  const float hh[3] = { h0, h1, h2 };
  #pragma unroll 1
  for (int d = 0; d < 8; d++) {
    float acc[9] = {0,0,0,0,0,0,0,0,0};
    #pragma unroll
    for (int l = 0; l < 8; l++) {
      const float el = enc[l];
      const float* p = P022 + (d*8 + l)*8;
      #pragma unroll
      for (int b = 0; b < 8; b++) {
        const float pe = el*p[b];
        #pragma unroll
        for (int k = 0; k < 9; k++) acc[k] += pe*X[b][k];
      }
    }
    const float sd = scd[d];
    const float q[3] = { Q0[d], Q1[d], Q2[d] };
    #pragma unroll
    for (int i = 0; i < 3; i++) {
      const float hi = hh[i];
      #pragma unroll
      for (int j = 0; j < 3; j++) {
        float r = acc[3*i + j] + hi*q[j] + hi*hh[j]*sd;
        atomicAdd(outD + d*9 + 3*i + j, 0.1f*r);
      }
    }
  }
}

extern "C" void kernel_launch(void* const* d_in, const int* in_sizes, int n_in,
                              void* d_out, int out_size, void* d_ws, size_t ws_size,
                              hipStream_t stream) {
  const float* r_ij = (const float*)d_in[0];
  const float* x_a  = (const float*)d_in[1];
  const float* x_v  = (const float*)d_in[2];
  const float* x_d  = (const float*)d_in[3];
  const float* P000 = (const float*)d_in[4];
  const float* P110 = (const float*)d_in[5];
  const float* P220 = (const float*)d_in[6];
  const float* P011 = (const float*)d_in[7];
  const float* P101 = (const float*)d_in[8];
  const float* P121 = (const float*)d_in[9];
  const float* P211 = (const float*)d_in[10];
  const float* P111 = (const float*)d_in[11];
  const float* P022 = (const float*)d_in[12];
  const float* P202 = (const float*)d_in[13];
  const float* P112 = (const float*)d_in[14];
  const float* P222 = (const float*)d_in[15];
  const float* P212 = (const float*)d_in[16];
  const int* src = (const int*)d_in[17];
  const int* dst = (const int*)d_in[18];

  const int E = in_sizes[17];
  const int N = in_sizes[1] / 32;
  float* out = (float*)d_out;

  // atomics accumulate into out: must zero every call (graph-capture-safe stream memset)
  hipMemsetAsync(d_out, 0, (size_t)out_size * sizeof(float), stream);

  const int grid = (E + BLK - 1) / BLK;
  const size_t need = 256 + (size_t)E * sizeof(int);
  int* cnt = nullptr;
  int* list = nullptr;
  if (ws_size >= need) {
    cnt  = (int*)d_ws;
    list = (int*)((char*)d_ws + 256);
    hipMemsetAsync(d_ws, 0, 256, stream);
    compact_k<<<grid, BLK, 0, stream>>>(r_ij, E, cnt, list);
  }
  msg_k<<<grid, BLK, 0, stream>>>(r_ij, x_a, x_v, x_d,
                                  P000, P110, P220, P011, P101, P121, P211, P111,
                                  P022, P202, P112, P222, P212,
                                  src, dst, cnt, list, E, N, out);
}

// Round 2
// 1618.544 us; speedup vs baseline: 1.0882x; 1.0882x over previous
//
#include <hip/hip_runtime.h>

#define PI_F 3.14159265358979323846f

// ---------------- edge geometry: radial encoding + squashed direction ----------------
struct EdgeGeom { float enc[8]; float h0, h1, h2; };

__device__ __forceinline__ bool edge_geom(const float* __restrict__ r_ij, int e, EdgeGeom& g) {
  const float rx = r_ij[3*e], ry = r_ij[3*e+1], rz = r_ij[3*e+2];
  const float xsq = (rx*rx + ry*ry + rz*rz) * (1.0f/2.5f);
  const float cut = 1.0f - xsq;
  if (cut <= 0.0f) return false;
  const float th = PI_F * sqrtf(xsq);
  const float c1 = cosf(th);
  g.enc[0] = cut; g.enc[1] = c1*cut;
  float cp = 1.0f, cc = c1;
  #pragma unroll
  for (int n = 2; n < 8; n++) { float cn = 2.0f*c1*cc - cp; cp = cc; cc = cn; g.enc[n] = cn*cut; }
  const float s = 7.0f/2.5f;
  const float yx = rx*s, yy = ry*s, yz = rz*s;
  const float inv = rsqrtf(1.0f + yx*yx + yy*yy + yz*yz);
  g.h0 = yx*inv; g.h1 = yy*inv; g.h2 = yz*inv;
  return true;
}

__device__ __forceinline__ int edge_id(const int* __restrict__ cnt, const int* __restrict__ list,
                                       int t, int E) {
  if (list != nullptr) { if (t >= *cnt) return -1; return list[t]; }
  if (t >= E) return -1;
  return t;
}

// ---------------- compaction ----------------
__global__ __launch_bounds__(256) void compact_k(const float* __restrict__ r, int E,
                                                 int* __restrict__ cnt, int* __restrict__ list) {
  int e = blockIdx.x * 256 + threadIdx.x;
  if (e >= E) return;
  float rx = r[3*e], ry = r[3*e+1], rz = r[3*e+2];
  float xsq = (rx*rx + ry*ry + rz*rz) * (1.0f/2.5f);
  if (xsq < 1.0f) {
    int p = atomicAdd(cnt, 1);
    list[p] = e;
  }
}

// ---------------- rank-0 messages: psi_a ----------------
// LDS: P000 (32*8*32=8192) | P110 (32*8*16=4096) | P220 (32*8*8=2048) = 14336 floats (57 KB)
static constexpr int BLKA = 512;
__global__ __launch_bounds__(BLKA) void msgA_k(
    const float* __restrict__ r_ij, const float* __restrict__ x_a,
    const float* __restrict__ x_v,  const float* __restrict__ x_d,
    const float* __restrict__ P000, const float* __restrict__ P110, const float* __restrict__ P220,
    const int* __restrict__ src, const int* __restrict__ dst,
    const int* __restrict__ cnt, const int* __restrict__ list, int E,
    float* __restrict__ outA)
{
  __shared__ float sP[14336];
  for (int i = threadIdx.x; i < 8192; i += BLKA) sP[i]        = P000[i];
  for (int i = threadIdx.x; i < 4096; i += BLKA) sP[8192+i]   = P110[i];
  for (int i = threadIdx.x; i < 2048; i += BLKA) sP[12288+i]  = P220[i];
  __syncthreads();

  const int t = blockIdx.x * BLKA + threadIdx.x;
  const int e = edge_id(cnt, list, t, E);
  if (e < 0) return;
  EdgeGeom g;
  if (!edge_geom(r_ij, e, g)) return;

  const int nj = dst[e], ni = src[e];
  const float* __restrict__ xaj = x_a + (size_t)nj*32;
  const float* __restrict__ xvj = x_v + (size_t)nj*48;
  const float* __restrict__ xdj = x_d + (size_t)nj*72;

  // c[56] = [xa (32) | s1 = h.xv (16) | s2 = h^T xd h (8)]
  float c[56];
  #pragma unroll
  for (int b = 0; b < 32; b++) c[b] = xaj[b];
  #pragma unroll
  for (int b = 0; b < 16; b++)
    c[32+b] = g.h0*xvj[3*b] + g.h1*xvj[3*b+1] + g.h2*xvj[3*b+2];
  #pragma unroll
  for (int b = 0; b < 8; b++) {
    const float* m = xdj + 9*b;
    float t0 = g.h0*m[0] + g.h1*m[3] + g.h2*m[6];
    float t1 = g.h0*m[1] + g.h1*m[4] + g.h2*m[7];
    float t2 = g.h0*m[2] + g.h1*m[5] + g.h2*m[8];
    c[48+b] = g.h0*t0 + g.h1*t1 + g.h2*t2;
  }

  float* o = outA + (size_t)ni*32;
  const float* __restrict__ s000 = sP;
  const float* __restrict__ s110 = sP + 8192;
  const float* __restrict__ s220 = sP + 12288;
  #pragma unroll 1
  for (int a = 0; a < 32; a++) {
    float acc = 0.0f;
    #pragma unroll
    for (int l = 0; l < 8; l++) {
      const float* p0 = s000 + (a*8 + l)*32;
      const float* p1 = s110 + (a*8 + l)*16;
      const float* p2 = s220 + (a*8 + l)*8;
      float s = 0.0f;
      #pragma unroll
      for (int b = 0; b < 32; b++) s += p0[b]*c[b];
      #pragma unroll
      for (int b = 0; b < 16; b++) s += p1[b]*c[32+b];
      #pragma unroll
      for (int b = 0; b < 8;  b++) s += p2[b]*c[48+b];
      acc += g.enc[l]*s;
    }
    atomicAdd(o + a, 0.1f*acc);
  }
}

// ---------------- rank-1 messages: psi_v ----------------
// LDS: P011(2048) | P101(4096) | P121(1024) | P211(2048) | P111(2048) = 11264 floats (45 KB)
static constexpr int BLKV = 256;
__global__ __launch_bounds__(BLKV) void msgV_k(
    const float* __restrict__ r_ij, const float* __restrict__ x_a,
    const float* __restrict__ x_v,  const float* __restrict__ x_d,
    const float* __restrict__ P011, const float* __restrict__ P101, const float* __restrict__ P121,
    const float* __restrict__ P211, const float* __restrict__ P111,
    const int* __restrict__ src, const int* __restrict__ dst,
    const int* __restrict__ cnt, const int* __restrict__ list, int E,
    float* __restrict__ outV)
{
  __shared__ float sP[11264];
  for (int i = threadIdx.x; i < 2048; i += BLKV) sP[i]        = P011[i];
  for (int i = threadIdx.x; i < 4096; i += BLKV) sP[2048+i]   = P101[i];
  for (int i = threadIdx.x; i < 1024; i += BLKV) sP[6144+i]   = P121[i];
  for (int i = threadIdx.x; i < 2048; i += BLKV) sP[7168+i]   = P211[i];
  for (int i = threadIdx.x; i < 2048; i += BLKV) sP[9216+i]   = P111[i];
  __syncthreads();

  const int t = blockIdx.x * BLKV + threadIdx.x;
  const int e = edge_id(cnt, list, t, E);
  if (e < 0) return;
  EdgeGeom g;
  if (!edge_geom(r_ij, e, g)) return;

  const int nj = dst[e], ni = src[e];
  const float* __restrict__ xaj = x_a + (size_t)nj*32;
  const float* __restrict__ xvj = x_v + (size_t)nj*48;
  const float* __restrict__ xdj = x_d + (size_t)nj*72;

  const float* __restrict__ s011 = sP;
  const float* __restrict__ s101 = sP + 2048;
  const float* __restrict__ s121 = sP + 6144;
  const float* __restrict__ s211 = sP + 7168;
  const float* __restrict__ s111 = sP + 9216;

  // vector channel V and s1
  float V0[16], V1[16], V2[16], s1[16];
  #pragma unroll
  for (int b = 0; b < 16; b++) {
    float v0 = xvj[3*b], v1 = xvj[3*b+1], v2 = xvj[3*b+2];
    V0[b] = v0; V1[b] = v1; V2[b] = v2;
    s1[b] = g.h0*v0 + g.h1*v1 + g.h2*v2;
  }

  // phase 1: scv[v] = sum_l enc_l (P101 . xa  +  P211 . s1)
  float scv[16];
  {
    float xa[32];
    #pragma unroll
    for (int b = 0; b < 32; b++) xa[b] = xaj[b];
    #pragma unroll 1
    for (int v = 0; v < 16; v++) {
      float acc = 0.0f;
      #pragma unroll
      for (int l = 0; l < 8; l++) {
        const float* pa = s101 + (v*8 + l)*32;
        const float* pb = s211 + (v*8 + l)*16;
        float s = 0.0f;
        #pragma unroll
        for (int b = 0; b < 32; b++) s += pa[b]*xa[b];
        #pragma unroll
        for (int b = 0; b < 16; b++) s += pb[b]*s1[b];
        acc += g.enc[l]*s;
      }
      scv[v] = acc;
    }
  }

  // cross products and T = h^T xd
  float C0[16], C1[16], C2[16];
  #pragma unroll
  for (int b = 0; b < 16; b++) {
    C0[b] = g.h1*V2[b] - g.h2*V1[b];
    C1[b] = g.h2*V0[b] - g.h0*V2[b];
    C2[b] = g.h0*V1[b] - g.h1*V0[b];
  }
  float T0[8], T1[8], T2v[8];
  #pragma unroll
  for (int b = 0; b < 8; b++) {
    const float* m = xdj + 9*b;
    T0[b]  = g.h0*m[0] + g.h1*m[3] + g.h2*m[6];
    T1[b]  = g.h0*m[1] + g.h1*m[4] + g.h2*m[7];
    T2v[b] = g.h0*m[2] + g.h1*m[5] + g.h2*m[8];
  }

  float* o = outV + (size_t)ni*48;
  #pragma unroll 1
  for (int v = 0; v < 16; v++) {
    float a0 = 0, a1 = 0, a2 = 0;
    #pragma unroll
    for (int l = 0; l < 8; l++) {
      const float el = g.enc[l];
      const float* p011 = s011 + (v*8 + l)*16;
      const float* p121 = s121 + (v*8 + l)*8;
      const float* p111 = s111 + (v*8 + l)*16;
      float t0 = 0, t1 = 0, t2 = 0;
      #pragma unroll
      for (int b = 0; b < 16; b++) { float p = p011[b]; t0 += p*V0[b]; t1 += p*V1[b]; t2 += p*V2[b]; }
      #pragma unroll
      for (int b = 0; b < 8;  b++) { float p = p121[b]; t0 += p*T0[b]; t1 += p*T1[b]; t2 += p*T2v[b]; }
      #pragma unroll
      for (int b = 0; b < 16; b++) { float p = p111[b]; t0 += p*C0[b]; t1 += p*C1[b]; t2 += p*C2[b]; }
      a0 += el*t0; a1 += el*t1; a2 += el*t2;
    }
    const float sv = scv[v];
    atomicAdd(o + v*3 + 0, 0.1f*(a0 + g.h0*sv));
    atomicAdd(o + v*3 + 1, 0.1f*(a1 + g.h1*sv));
    atomicAdd(o + v*3 + 2, 0.1f*(a2 + g.h2*sv));
  }
}

// ---------------- rank-2 messages: psi_d ----------------
// LDS: P022(512) | P202(2048) | P112(1024) | P222(512) | P212(1024) = 5120 floats (20 KB)
static constexpr int BLKD = 256;
__global__ __launch_bounds__(BLKD) void msgD_k(
    const float* __restrict__ r_ij, const float* __restrict__ x_a,
    const float* __restrict__ x_v,  const float* __restrict__ x_d,
    const float* __restrict__ P022, const float* __restrict__ P202, const float* __restrict__ P112,
    const float* __restrict__ P222, const float* __restrict__ P212,
    const int* __restrict__ src, const int* __restrict__ dst,
    const int* __restrict__ cnt, const int* __restrict__ list, int E,
    float* __restrict__ outD)
{
  __shared__ float sP[5120];
  for (int i = threadIdx.x; i < 512;  i += BLKD) sP[i]        = P022[i];
  for (int i = threadIdx.x; i < 2048; i += BLKD) sP[512+i]    = P202[i];
  for (int i = threadIdx.x; i < 1024; i += BLKD) sP[2560+i]   = P112[i];
  for (int i = threadIdx.x; i < 512;  i += BLKD) sP[3584+i]   = P222[i];
  for (int i = threadIdx.x; i < 1024; i += BLKD) sP[4096+i]   = P212[i];
  __syncthreads();

  const int t = blockIdx.x * BLKD + threadIdx.x;
  const int e = edge_id(cnt, list, t, E);
  if (e < 0) return;
  EdgeGeom g;
  if (!edge_geom(r_ij, e, g)) return;

  const int nj = dst[e], ni = src[e];
  const float* __restrict__ xaj = x_a + (size_t)nj*32;
  const float* __restrict__ xvj = x_v + (size_t)nj*48;
  const float* __restrict__ xdj = x_d + (size_t)nj*72;

  const float* __restrict__ s022 = sP;
  const float* __restrict__ s202 = sP + 512;
  const float* __restrict__ s112 = sP + 2560;
  const float* __restrict__ s222 = sP + 3584;
  const float* __restrict__ s212 = sP + 4096;

  // phase 1: scd[d] = sum_l enc_l (P202 . xa)
  float scd[8];
  {
    float xa[32];
    #pragma unroll
    for (int b = 0; b < 32; b++) xa[b] = xaj[b];
    #pragma unroll 1
    for (int d = 0; d < 8; d++) {
      float acc = 0.0f;
      #pragma unroll
      for (int l = 0; l < 8; l++) {
        const float* p = s202 + (d*8 + l)*32;
        float s = 0.0f;
        #pragma unroll
        for (int b = 0; b < 32; b++) s += p[b]*xa[b];
        acc += g.enc[l]*s;
      }
      scd[d] = acc;
    }
  }

  // phase 2: Q[d][j] from V, CR, T
  float Q0[8], Q1[8], Q2[8];
  {
    float V0[16], V1[16], V2[16], C0[16], C1[16], C2[16];
    #pragma unroll
    for (int b = 0; b < 16; b++) {
      float v0 = xvj[3*b], v1 = xvj[3*b+1], v2 = xvj[3*b+2];
      V0[b] = v0; V1[b] = v1; V2[b] = v2;
      C0[b] = g.h1*v2 - g.h2*v1;
      C1[b] = g.h2*v0 - g.h0*v2;
      C2[b] = g.h0*v1 - g.h1*v0;
    }
    float T0[8], T1[8], T2v[8];
    #pragma unroll
    for (int b = 0; b < 8; b++) {
      const float* m = xdj + 9*b;
      T0[b]  = g.h0*m[0] + g.h1*m[3] + g.h2*m[6];
      T1[b]  = g.h0*m[1] + g.h1*m[4] + g.h2*m[7];
      T2v[b] = g.h0*m[2] + g.h1*m[5] + g.h2*m[8];
    }
    #pragma unroll 1
    for (int d = 0; d < 8; d++) {
      float a0 = 0, a1 = 0, a2 = 0;
      #pragma unroll
      for (int l = 0; l < 8; l++) {
        const float el = g.enc[l];
        const float* p112 = s112 + (d*8 + l)*16;
        const float* p222 = s222 + (d*8 + l)*8;
        const float* p212 = s212 + (d*8 + l)*16;
        float t0 = 0, t1 = 0, t2 = 0;
        #pragma unroll
        for (int b = 0; b < 16; b++) { float p = p112[b]; t0 += p*V0[b]; t1 += p*V1[b]; t2 += p*V2[b]; }
        #pragma unroll
        for (int b = 0; b < 8;  b++) { float p = p222[b]; t0 += p*T0[b]; t1 += p*T1[b]; t2 += p*T2v[b]; }
        #pragma unroll
        for (int b = 0; b < 16; b++) { float p = p212[b]; t0 += p*C0[b]; t1 += p*C1[b]; t2 += p*C2[b]; }
        a0 += el*t0; a1 += el*t1; a2 += el*t2;
      }
      Q0[d] = a0; Q1[d] = a1; Q2[d] = a2;
    }
  }

  // phase 3: psi_d = P022 (x) X  +  h_i Q_j  +  h_i h_j scd
  float X[8][9];
  #pragma unroll
  for (int b = 0; b < 8; b++) {
    #pragma unroll
    for (int k = 0; k < 9; k++) X[b][k] = xdj[9*b + k];
  }
  const float hh[3] = { g.h0, g.h1, g.h2 };
  float* o = outD + (size_t)ni*72;
  #pragma unroll 1
  for (int d = 0; d < 8; d++) {
    float acc[9] = {0,0,0,0,0,0,0,0,0};
    #pragma unroll
    for (int l = 0; l < 8; l++) {
      const float el = g.enc[l];
      const float* p = s022 + (d*8 + l)*8;
      #pragma unroll
      for (int b = 0; b < 8; b++) {
        const float pe = el*p[b];
        #pragma unroll
        for (int k = 0; k < 9; k++) acc[k] += pe*X[b][k];
      }
    }
    const float sd = scd[d];
    const float q[3] = { Q0[d], Q1[d], Q2[d] };
    #pragma unroll
    for (int i = 0; i < 3; i++) {
      const float hi = hh[i];
      #pragma unroll
      for (int j = 0; j < 3; j++) {
        atomicAdd(o + d*9 + 3*i + j, 0.1f*(acc[3*i + j] + hi*q[j] + hi*hh[j]*sd));
      }
    }
  }
}

extern "C" void kernel_launch(void* const* d_in, const int* in_sizes, int n_in,
                              void* d_out, int out_size, void* d_ws, size_t ws_size,
                              hipStream_t stream) {
  const float* r_ij = (const float*)d_in[0];
  const float* x_a  = (const float*)d_in[1];
  const float* x_v  = (const float*)d_in[2];
  const float* x_d  = (const float*)d_in[3];
  const float* P000 = (const float*)d_in[4];
  const float* P110 = (const float*)d_in[5];
  const float* P220 = (const float*)d_in[6];
  const float* P011 = (const float*)d_in[7];
  const float* P101 = (const float*)d_in[8];
  const float* P121 = (const float*)d_in[9];
  const float* P211 = (const float*)d_in[10];
  const float* P111 = (const float*)d_in[11];
  const float* P022 = (const float*)d_in[12];
  const float* P202 = (const float*)d_in[13];
  const float* P112 = (const float*)d_in[14];
  const float* P222 = (const float*)d_in[15];
  const float* P212 = (const float*)d_in[16];
  const int* src = (const int*)d_in[17];
  const int* dst = (const int*)d_in[18];

  const int E = in_sizes[17];
  const int N = in_sizes[1] / 32;
  float* out = (float*)d_out;
  float* outA = out;
  float* outV = out + (size_t)N*32;
  float* outD = out + (size_t)N*80;

  hipMemsetAsync(d_out, 0, (size_t)out_size * sizeof(float), stream);

  const size_t need = 256 + (size_t)E * sizeof(int);
  int* cnt = nullptr;
  int* list = nullptr;
  if (ws_size >= need) {
    cnt  = (int*)d_ws;
    list = (int*)((char*)d_ws + 256);
    hipMemsetAsync(d_ws, 0, 256, stream);
    compact_k<<<(E + 255)/256, 256, 0, stream>>>(r_ij, E, cnt, list);
  }

  msgA_k<<<(E + BLKA - 1)/BLKA, BLKA, 0, stream>>>(r_ij, x_a, x_v, x_d,
      P000, P110, P220, src, dst, cnt, list, E, outA);
  msgV_k<<<(E + BLKV - 1)/BLKV, BLKV, 0, stream>>>(r_ij, x_a, x_v, x_d,
      P011, P101, P121, P211, P111, src, dst, cnt, list, E, outV);
  msgD_k<<<(E + BLKD - 1)/BLKD, BLKD, 0, stream>>>(r_ij, x_a, x_v, x_d,
      P022, P202, P112, P222, P212, src, dst, cnt, list, E, outD);
}